// Round 7
// baseline (802.273 us; speedup 1.0000x reference)
//
#include <hip/hip_runtime.h>

#define N_NODES 100000
#define N_EDGES 1600000
#define TILES 6250           // 100000/16

#define NPB 128              // nodes per bucket
#define NB 782               // ceil(100000/128)
#define SUBS 64              // one sub-region per scatter block
#define CAP 60               // slots per (bucket, sub); mean 32, ~5 sigma
#define OVF_CAP 16384

typedef __attribute__((ext_vector_type(8))) short short8;
typedef __attribute__((ext_vector_type(4))) float f32x4;

static __device__ __forceinline__ unsigned short f2bf(float f) {
    unsigned int u = __float_as_uint(f);
    unsigned int r = (u + 0x7fffu + ((u >> 16) & 1u)) >> 16;  // RNE
    return (unsigned short)r;
}
static __device__ __forceinline__ float bfl(unsigned int u) {
    return __uint_as_float(u << 16);
}
static __device__ __forceinline__ float bfh(unsigned int u) {
    return __uint_as_float(u & 0xffff0000u);
}

// g = bf16(feat @ W^T). Verified in round 6 (absmax 0.125). A and B frags use
// the same k-index formula so any consistent k-permutation cancels; C/D
// mapping col=lane&15, row=(lane>>4)*4+reg (m89).
__global__ __launch_bounds__(256) void gcn_gemm(
    const float* __restrict__ feat, const float* __restrict__ W,
    unsigned int* __restrict__ g32) {
    int l = threadIdx.x & 63, wv = threadIdx.x >> 6;
    int r = l & 15, c = l >> 4;

    short8 bf[4][2];
#pragma unroll
    for (int t = 0; t < 4; ++t)
#pragma unroll
        for (int s = 0; s < 2; ++s) {
            const float* wp = W + (16 * t + r) * 64 + 32 * s + c * 8;
            float4 w0 = *(const float4*)wp;
            float4 w1 = *(const float4*)(wp + 4);
            short8 f;
            f[0] = (short)f2bf(w0.x); f[1] = (short)f2bf(w0.y);
            f[2] = (short)f2bf(w0.z); f[3] = (short)f2bf(w0.w);
            f[4] = (short)f2bf(w1.x); f[5] = (short)f2bf(w1.y);
            f[6] = (short)f2bf(w1.z); f[7] = (short)f2bf(w1.w);
            bf[t][s] = f;
        }

    int tile0 = (blockIdx.x * 4 + wv) * 4;
#pragma unroll
    for (int ti = 0; ti < 4; ++ti) {
        int tile = tile0 + ti;
        if (tile >= TILES) break;
        int m0 = tile * 16;
        f32x4 acc0 = {0,0,0,0}, acc1 = {0,0,0,0}, acc2 = {0,0,0,0}, acc3 = {0,0,0,0};
#pragma unroll
        for (int s = 0; s < 2; ++s) {
            const float* ap = feat + (m0 + r) * 64 + 32 * s + c * 8;
            float4 a0 = *(const float4*)ap;
            float4 a1 = *(const float4*)(ap + 4);
            short8 af;
            af[0] = (short)f2bf(a0.x); af[1] = (short)f2bf(a0.y);
            af[2] = (short)f2bf(a0.z); af[3] = (short)f2bf(a0.w);
            af[4] = (short)f2bf(a1.x); af[5] = (short)f2bf(a1.y);
            af[6] = (short)f2bf(a1.z); af[7] = (short)f2bf(a1.w);
            acc0 = __builtin_amdgcn_mfma_f32_16x16x32_bf16(af, bf[0][s], acc0, 0, 0, 0);
            acc1 = __builtin_amdgcn_mfma_f32_16x16x32_bf16(af, bf[1][s], acc1, 0, 0, 0);
            acc2 = __builtin_amdgcn_mfma_f32_16x16x32_bf16(af, bf[2][s], acc2, 0, 0, 0);
            acc3 = __builtin_amdgcn_mfma_f32_16x16x32_bf16(af, bf[3][s], acc3, 0, 0, 0);
        }
#pragma unroll
        for (int t = 0; t < 4; ++t) {
            f32x4 a = (t == 0) ? acc0 : (t == 1) ? acc1 : (t == 2) ? acc2 : acc3;
#pragma unroll
            for (int reg = 0; reg < 4; ++reg) {
                float d = a[reg];
                float o = __shfl_xor(d, 1);
                if (!(l & 1)) {
                    int m = m0 + c * 4 + reg;
                    int n = 16 * t + r;
                    g32[(m * 64 + n) >> 1] =
                        (unsigned int)f2bf(d) | ((unsigned int)f2bf(o) << 16);
                }
            }
        }
    }
}

// Phase 1: bin edges by dst bucket into per-(bucket, block) sub-regions.
// Single writer per region -> tail lines stay dirty in ONE L2 (no cross-XCD
// partial-line ping-pong). 1 atomic + 1 store per edge.
__global__ __launch_bounds__(1024) void gcn_bucket(
    const int* __restrict__ src, const int* __restrict__ dst,
    unsigned int* __restrict__ cursor, unsigned int* __restrict__ region,
    unsigned int* __restrict__ ovf_cnt, uint2* __restrict__ ovf) {
    int sub = blockIdx.x;                     // grid = SUBS blocks
    const int stride = SUBS * 1024;
    for (int i = blockIdx.x * 1024 + threadIdx.x; i < N_EDGES; i += stride) {
        int s = src[i];
        int d = dst[i];
        int rb = (d >> 7) * SUBS + sub;
        unsigned int c = atomicAdd(&cursor[rb], 1u);
        unsigned int v = ((unsigned int)(d & 127) << 17) | (unsigned int)s;
        if (c < CAP) {
            region[rb * CAP + c] = v;
        } else {
            unsigned int o = atomicAdd(ovf_cnt, 1u);
            if (o < OVF_CAP) ovf[o] = make_uint2((unsigned int)s, (unsigned int)d);
        }
    }
}

// Phase 2: one block per bucket; acc[128][64] f32 in LDS (32 KB), init with
// bias. 16-lane groups read one transformed bf16 row (128B) per edge and
// ds_add_f32 into the LDS accumulator. Epilogue: relu + float4 store.
__global__ __launch_bounds__(512) void gcn_gather2(
    const uint2* __restrict__ g64, const unsigned int* __restrict__ cursor,
    const unsigned int* __restrict__ region, const unsigned int* __restrict__ ovf_cnt,
    const uint2* __restrict__ ovf, const float* __restrict__ bias,
    float* __restrict__ out) {
    __shared__ float acc[NPB][64];
    int b = blockIdx.x;
    int tid = threadIdx.x;
    for (int i = tid; i < NPB * 64; i += 512) acc[i >> 6][i & 63] = bias[i & 63];
    __syncthreads();

    int wv = tid >> 6, l = tid & 63, grp = l >> 4, k = l & 15;
    for (int sub = wv; sub < SUBS; sub += 8) {
        int rb = b * SUBS + sub;
        int cnt = (int)min(cursor[rb], (unsigned int)CAP);
        const unsigned int* rp = region + rb * CAP;
        int j = 0;
        for (; j + 8 <= cnt; j += 8) {     // 2 g-loads in flight
            unsigned int v0 = rp[j + grp];
            unsigned int v1 = rp[j + 4 + grp];
            uint2 w0 = g64[(v0 & 0x1FFFFu) * 16 + k];
            uint2 w1 = g64[(v1 & 0x1FFFFu) * 16 + k];
            float* a0 = &acc[v0 >> 17][4 * k];
            atomicAdd(a0 + 0, bfl(w0.x)); atomicAdd(a0 + 1, bfh(w0.x));
            atomicAdd(a0 + 2, bfl(w0.y)); atomicAdd(a0 + 3, bfh(w0.y));
            float* a1 = &acc[v1 >> 17][4 * k];
            atomicAdd(a1 + 0, bfl(w1.x)); atomicAdd(a1 + 1, bfh(w1.x));
            atomicAdd(a1 + 2, bfl(w1.y)); atomicAdd(a1 + 3, bfh(w1.y));
        }
        for (; j < cnt; j += 4) {
            int rem = cnt - j;
            if (grp < rem) {
                unsigned int v = rp[j + grp];
                uint2 w = g64[(v & 0x1FFFFu) * 16 + k];
                float* a = &acc[v >> 17][4 * k];
                atomicAdd(a + 0, bfl(w.x)); atomicAdd(a + 1, bfh(w.x));
                atomicAdd(a + 2, bfl(w.y)); atomicAdd(a + 3, bfh(w.y));
            }
        }
    }

    // overflow spill list (expected empty; correct regardless)
    unsigned int oc = *ovf_cnt;
    if (oc > OVF_CAP) oc = OVF_CAP;
    for (unsigned int i = (unsigned int)wv; i < oc; i += 8) {
        uint2 e = ovf[i];
        if ((int)(e.y >> 7) == b && l < 32) {
            unsigned int w = ((const unsigned int*)g64)[e.x * 32 + l];
            int dl = e.y & 127;
            atomicAdd(&acc[dl][2 * l],     bfl(w));
            atomicAdd(&acc[dl][2 * l + 1], bfh(w));
        }
    }
    __syncthreads();

    int node0 = b * NPB;
    for (int i = tid; i < NPB * 16; i += 512) {
        int node = node0 + (i >> 4);
        if (node < N_NODES) {
            float4 v = *(const float4*)&acc[i >> 4][(i & 15) * 4];
            v.x = fmaxf(v.x, 0.f); v.y = fmaxf(v.y, 0.f);
            v.z = fmaxf(v.z, 0.f); v.w = fmaxf(v.w, 0.f);
            *(float4*)(out + node * 64 + (i & 15) * 4) = v;
        }
    }
}

extern "C" void kernel_launch(void* const* d_in, const int* in_sizes, int n_in,
                              void* d_out, int out_size, void* d_ws, size_t ws_size,
                              hipStream_t stream) {
    const float* features = (const float*)d_in[0];
    const int*   src      = (const int*)d_in[1];
    const int*   dst      = (const int*)d_in[2];
    const float* W        = (const float*)d_in[3];
    const float* b        = (const float*)d_in[4];
    float* out = (float*)d_out;

    // Workspace (u32 units):
    //   cursor[50048->50176] | ovfcnt[64] | ovf[32768] | region[3002880] | g32[3200000]
    //   total 25.14 MB (round-1 proved >=25.6 MB available)
    unsigned int* ws    = (unsigned int*)d_ws;
    unsigned int* cursor  = ws;
    unsigned int* ovfcnt  = ws + 50176;
    uint2*        ovf     = (uint2*)(ws + 50240);
    unsigned int* region  = ws + 83008;
    unsigned int* g32     = ws + 3085888;

    // zero cursors + overflow count (201 KB)
    hipMemsetAsync(cursor, 0, (size_t)(50176 + 64) * sizeof(unsigned int), stream);

    gcn_gemm<<<(TILES + 15) / 16, 256, 0, stream>>>(features, W, g32);
    gcn_bucket<<<SUBS, 1024, 0, stream>>>(src, dst, cursor, region, ovfcnt, ovf);
    gcn_gather2<<<NB, 512, 0, stream>>>((const uint2*)g32, cursor, region,
                                        ovfcnt, ovf, b, out);
}

// Round 8
// 121.292 us; speedup vs baseline: 6.6144x; 6.6144x over previous
//
#include <hip/hip_runtime.h>

#define N_NODES 100000
#define N_EDGES 1600000
#define TILES 6250           // 100000/16

#define NPB 128              // nodes per bucket
#define NB 782               // ceil(100000/128)
#define SUBS 128             // binning blocks; region[sub][bucket] is PRIVATE to block sub
#define CAP 26               // slots per (sub,bucket); mean 16, ~2.5 sigma
#define OVF_CAP 8192
#define LISTCAP 3456         // SUBS*CAP + overflow slack

typedef __attribute__((ext_vector_type(8))) short short8;
typedef __attribute__((ext_vector_type(4))) float f32x4;

static __device__ __forceinline__ unsigned short f2bf(float f) {
    unsigned int u = __float_as_uint(f);
    unsigned int r = (u + 0x7fffu + ((u >> 16) & 1u)) >> 16;  // RNE
    return (unsigned short)r;
}
static __device__ __forceinline__ float bfl(unsigned int u) {
    return __uint_as_float(u << 16);
}
static __device__ __forceinline__ float bfh(unsigned int u) {
    return __uint_as_float(u & 0xffff0000u);
}

// g = bf16(feat @ W^T). Verified rounds 6-7 (absmax 0.125). A/B frags share
// the k-index formula (consistent k-permutation cancels); C/D per m89.
__global__ __launch_bounds__(256) void gcn_gemm(
    const float* __restrict__ feat, const float* __restrict__ W,
    unsigned int* __restrict__ g32) {
    int l = threadIdx.x & 63, wv = threadIdx.x >> 6;
    int r = l & 15, c = l >> 4;

    short8 bf[4][2];
#pragma unroll
    for (int t = 0; t < 4; ++t)
#pragma unroll
        for (int s = 0; s < 2; ++s) {
            const float* wp = W + (16 * t + r) * 64 + 32 * s + c * 8;
            float4 w0 = *(const float4*)wp;
            float4 w1 = *(const float4*)(wp + 4);
            short8 f;
            f[0] = (short)f2bf(w0.x); f[1] = (short)f2bf(w0.y);
            f[2] = (short)f2bf(w0.z); f[3] = (short)f2bf(w0.w);
            f[4] = (short)f2bf(w1.x); f[5] = (short)f2bf(w1.y);
            f[6] = (short)f2bf(w1.z); f[7] = (short)f2bf(w1.w);
            bf[t][s] = f;
        }

    int tile0 = (blockIdx.x * 4 + wv) * 4;
#pragma unroll
    for (int ti = 0; ti < 4; ++ti) {
        int tile = tile0 + ti;
        if (tile >= TILES) break;
        int m0 = tile * 16;
        f32x4 acc0 = {0,0,0,0}, acc1 = {0,0,0,0}, acc2 = {0,0,0,0}, acc3 = {0,0,0,0};
#pragma unroll
        for (int s = 0; s < 2; ++s) {
            const float* ap = feat + (m0 + r) * 64 + 32 * s + c * 8;
            float4 a0 = *(const float4*)ap;
            float4 a1 = *(const float4*)(ap + 4);
            short8 af;
            af[0] = (short)f2bf(a0.x); af[1] = (short)f2bf(a0.y);
            af[2] = (short)f2bf(a0.z); af[3] = (short)f2bf(a0.w);
            af[4] = (short)f2bf(a1.x); af[5] = (short)f2bf(a1.y);
            af[6] = (short)f2bf(a1.z); af[7] = (short)f2bf(a1.w);
            acc0 = __builtin_amdgcn_mfma_f32_16x16x32_bf16(af, bf[0][s], acc0, 0, 0, 0);
            acc1 = __builtin_amdgcn_mfma_f32_16x16x32_bf16(af, bf[1][s], acc1, 0, 0, 0);
            acc2 = __builtin_amdgcn_mfma_f32_16x16x32_bf16(af, bf[2][s], acc2, 0, 0, 0);
            acc3 = __builtin_amdgcn_mfma_f32_16x16x32_bf16(af, bf[3][s], acc3, 0, 0, 0);
        }
#pragma unroll
        for (int t = 0; t < 4; ++t) {
            f32x4 a = (t == 0) ? acc0 : (t == 1) ? acc1 : (t == 2) ? acc2 : acc3;
#pragma unroll
            for (int reg = 0; reg < 4; ++reg) {
                float d = a[reg];
                float o = __shfl_xor(d, 1);
                if (!(l & 1)) {
                    int m = m0 + c * 4 + reg;
                    int n = 16 * t + r;
                    g32[(m * 64 + n) >> 1] =
                        (unsigned int)f2bf(d) | ((unsigned int)f2bf(o) << 16);
                }
            }
        }
    }
}

// Single-pass binning, transposed-private layout: block `sub` is the ONLY
// writer of cursor[sub*NB+*] (3.1 KB) and region[(sub*NB+*)*CAP] (81 KB) --
// every dirty line has one writer -> no cross-XCD write amplification.
// Contiguous private edge range -> coalesced src/dst reads, single pass.
__global__ __launch_bounds__(512) void gcn_bin(
    const int* __restrict__ src, const int* __restrict__ dst,
    unsigned int* __restrict__ cursor, unsigned int* __restrict__ region,
    unsigned int* __restrict__ ovf_cnt, uint2* __restrict__ ovf) {
    int sub = blockIdx.x;
    int base = sub * (N_EDGES / SUBS);          // 12500 edges per block
    int end = base + (N_EDGES / SUBS);
    for (int i = base + threadIdx.x; i < end; i += 512) {
        int s = src[i];
        int d = dst[i];
        int bk = d >> 7;
        unsigned int c = atomicAdd(&cursor[sub * NB + bk], 1u);
        if (c < CAP) {
            region[(sub * NB + bk) * CAP + c] =
                ((unsigned int)(d & 127) << 17) | (unsigned int)s;
        } else {
            unsigned int o = atomicAdd(ovf_cnt, 1u);
            if (o < OVF_CAP) ovf[o] = make_uint2((unsigned int)s, (unsigned int)d);
        }
    }
}

// One block per bucket (128 nodes). Counting-sort the bucket's entries by
// node in LDS (int ops, no float RMW), then round-6-style per-node gather:
// 16-lane groups load one transformed 128B row per entry, register
// accumulate, shfl-reduce, bias+relu+float4 store.
__global__ __launch_bounds__(512) void gcn_gather3(
    const uint2* __restrict__ g64, const unsigned int* __restrict__ cursor,
    const unsigned int* __restrict__ region, const unsigned int* __restrict__ ovf_cnt,
    const uint2* __restrict__ ovf, const float* __restrict__ bias,
    float* __restrict__ out) {
    __shared__ unsigned int list[LISTCAP];
    __shared__ unsigned int sorted[LISTCAP];
    __shared__ unsigned int scnt[SUBS], soff[SUBS];
    __shared__ unsigned int cnt2[NPB], off2[NPB], cur2[NPB];
    __shared__ unsigned int ltot;

    int b = blockIdx.x;
    int tid = threadIdx.x;

    // per-sub counts for this bucket
    if (tid < SUBS) {
        unsigned int c = cursor[(unsigned)tid * NB + b];
        scnt[tid] = c < CAP ? c : CAP;
    }
    if (tid < NPB) cnt2[tid] = 0;
    __syncthreads();
    // inclusive scan of scnt -> soff
    if (tid < SUBS) soff[tid] = scnt[tid];
    __syncthreads();
    for (int off = 1; off < SUBS; off <<= 1) {
        unsigned int t = 0;
        if (tid < SUBS && tid >= off) t = soff[tid - off];
        __syncthreads();
        if (tid < SUBS) soff[tid] += t;
        __syncthreads();
    }
    if (tid == 0) ltot = soff[SUBS - 1];
    __syncthreads();

    // copy region entries to packed list (writes [0, base_total) )
    for (int idx = tid; idx < SUBS * CAP; idx += 512) {
        int s = idx / CAP, slot = idx - s * CAP;
        if (slot < (int)scnt[s])
            list[soff[s] - scnt[s] + slot] = region[((unsigned)s * NB + b) * CAP + slot];
    }
    // append this bucket's overflow entries (appends at >= base_total)
    unsigned int oc = *ovf_cnt;
    if (oc > OVF_CAP) oc = OVF_CAP;
    for (unsigned int i = tid; i < oc; i += 512) {
        uint2 e = ovf[i];
        if ((int)(e.y >> 7) == b) {
            unsigned int p = atomicAdd(&ltot, 1u);
            if (p < LISTCAP) list[p] = ((e.y & 127u) << 17) | e.x;
        }
    }
    __syncthreads();
    unsigned int T = ltot < LISTCAP ? ltot : LISTCAP;

    // count per node, scan, place (counting sort by dl = entry>>17)
    for (unsigned int i = tid; i < T; i += 512)
        atomicAdd(&cnt2[list[i] >> 17], 1u);
    __syncthreads();
    if (tid < NPB) off2[tid] = cnt2[tid];
    __syncthreads();
    for (int off = 1; off < NPB; off <<= 1) {
        unsigned int t = 0;
        if (tid < NPB && tid >= off) t = off2[tid - off];
        __syncthreads();
        if (tid < NPB) off2[tid] += t;
        __syncthreads();
    }
    if (tid < NPB) cur2[tid] = off2[tid] - cnt2[tid];
    __syncthreads();
    for (unsigned int i = tid; i < T; i += 512) {
        unsigned int v = list[i];
        unsigned int p = atomicAdd(&cur2[v >> 17], 1u);
        if (p < LISTCAP) sorted[p] = v & 0x1FFFFu;
    }
    __syncthreads();

    // per-node gather: wave wv owns nodes dl = wv*16 .. wv*16+15
    int wv = tid >> 6, l = tid & 63, grp = l >> 4, k = l & 15;
    for (int n = 0; n < 16; ++n) {
        int dl = wv * 16 + n;
        int node = b * NPB + dl;
        if (node >= N_NODES) break;   // wave-uniform
        unsigned int start = off2[dl] - cnt2[dl];
        int cnt = (int)cnt2[dl];
        float a0 = 0.f, a1 = 0.f, a2 = 0.f, a3 = 0.f;
        int j = 0;
        for (; j + 8 <= cnt; j += 8) {
            unsigned int s0 = sorted[start + j + grp];
            unsigned int s1 = sorted[start + j + 4 + grp];
            uint2 w0 = g64[s0 * 16 + k];
            uint2 w1 = g64[s1 * 16 + k];
            a0 += bfl(w0.x); a1 += bfh(w0.x); a2 += bfl(w0.y); a3 += bfh(w0.y);
            a0 += bfl(w1.x); a1 += bfh(w1.x); a2 += bfl(w1.y); a3 += bfh(w1.y);
        }
        for (; j < cnt; j += 4) {
            if (j + grp < cnt) {
                unsigned int s0 = sorted[start + j + grp];
                uint2 w = g64[s0 * 16 + k];
                a0 += bfl(w.x); a1 += bfh(w.x); a2 += bfl(w.y); a3 += bfh(w.y);
            }
        }
        a0 += __shfl_xor(a0, 16); a0 += __shfl_xor(a0, 32);
        a1 += __shfl_xor(a1, 16); a1 += __shfl_xor(a1, 32);
        a2 += __shfl_xor(a2, 16); a2 += __shfl_xor(a2, 32);
        a3 += __shfl_xor(a3, 16); a3 += __shfl_xor(a3, 32);
        if (l < 16) {
            float4 b4 = *(const float4*)(bias + 4 * l);
            float4 o;
            o.x = fmaxf(a0 + b4.x, 0.0f);
            o.y = fmaxf(a1 + b4.y, 0.0f);
            o.z = fmaxf(a2 + b4.z, 0.0f);
            o.w = fmaxf(a3 + b4.w, 0.0f);
            *(float4*)(out + node * 64 + 4 * l) = o;
        }
    }
}

extern "C" void kernel_launch(void* const* d_in, const int* in_sizes, int n_in,
                              void* d_out, int out_size, void* d_ws, size_t ws_size,
                              hipStream_t stream) {
    const float* features = (const float*)d_in[0];
    const int*   src      = (const int*)d_in[1];
    const int*   dst      = (const int*)d_in[2];
    const float* W        = (const float*)d_in[3];
    const float* b        = (const float*)d_in[4];
    float* out = (float*)d_out;

    // Workspace (u32): cursor[100096] | ovfcnt[64] | ovf[16384] |
    //                  region[2602496] | g32[3200000]  -- total 23.7 MB
    unsigned int* ws     = (unsigned int*)d_ws;
    unsigned int* cursor = ws;
    unsigned int* ovfcnt = ws + 100096;
    uint2*        ovf    = (uint2*)(ws + 100160);
    unsigned int* region = ws + 116544;
    unsigned int* g32    = ws + 2719040;

    hipMemsetAsync(cursor, 0, (size_t)(100096 + 64) * sizeof(unsigned int), stream);

    gcn_gemm<<<(TILES + 15) / 16, 256, 0, stream>>>(features, W, g32);
    gcn_bin<<<SUBS, 512, 0, stream>>>(src, dst, cursor, region, ovfcnt, ovf);
    gcn_gather3<<<NB, 512, 0, stream>>>((const uint2*)g32, cursor, region,
                                        ovfcnt, ovf, b, out);
}